// Round 4
// baseline (8079.282 us; speedup 1.0000x reference)
//
#include <hip/hip_runtime.h>
#include <hip/hip_bf16.h>

#define BB 128
#define NN 49
#define VV 10000
#define TT 20

typedef short s8x8 __attribute__((ext_vector_type(8)));
typedef __bf16 bf8x8 __attribute__((ext_vector_type(8)));
typedef float f32x4 __attribute__((ext_vector_type(4)));

__device__ __forceinline__ short f2bf(float f){ return __builtin_bit_cast(short, (__bf16)f); }

__device__ __forceinline__ s8x8 cast8(const float* p){
  float4 a = *(const float4*)p;
  float4 b = *(const float4*)(p + 4);
  s8x8 r;
  r[0] = f2bf(a.x); r[1] = f2bf(a.y); r[2] = f2bf(a.z); r[3] = f2bf(a.w);
  r[4] = f2bf(b.x); r[5] = f2bf(b.y); r[6] = f2bf(b.z); r[7] = f2bf(b.w);
  return r;
}

__device__ __forceinline__ f32x4 mfma16(s8x8 a, s8x8 b, f32x4 c){
  return __builtin_amdgcn_mfma_f32_16x16x32_bf16(
      __builtin_bit_cast(bf8x8, a), __builtin_bit_cast(bf8x8, b), c, 0, 0, 0);
}

// ---------------------------------------------------------------------------
// fvp[r][e] = sum_d img[r][d] * Wv[e][d] + att_b[r % 49]   (fp32, VALU)
// grid: 392 blocks x 256 thr; block handles 16 rows x all 512 cols.
// ---------------------------------------------------------------------------
__global__ __launch_bounds__(256) void k_fv(const float* __restrict__ img,
    const float* __restrict__ Wv, const float* __restrict__ attb,
    float* __restrict__ fvp)
{
  const int r0 = blockIdx.x * 16;
  __shared__ float xs[16][512];
  const int tid = threadIdx.x;
  for (int i = tid; i < 16*512; i += 256)
    xs[i>>9][i&511] = img[(long)r0*512 + i];
  __syncthreads();
  float acc0[16], acc1[16];
  #pragma unroll
  for (int r = 0; r < 16; r++){ acc0[r] = 0.f; acc1[r] = 0.f; }
  const float* w0p = Wv + (long)tid*512;
  const float* w1p = Wv + (long)(tid+256)*512;
  for (int d = 0; d < 512; d++){
    float w0 = w0p[d], w1 = w1p[d];
    #pragma unroll
    for (int r = 0; r < 16; r++){
      float xv = xs[r][d];
      acc0[r] = fmaf(xv, w0, acc0[r]);
      acc1[r] = fmaf(xv, w1, acc1[r]);
    }
  }
  for (int r = 0; r < 16; r++){
    float ab = attb[(r0 + r) % NN];
    fvp[(long)(r0+r)*512 + tid]       = acc0[r] + ab;
    fvp[(long)(r0+r)*512 + tid + 256] = acc1[r] + ab;
  }
}

// ---------------------------------------------------------------------------
// Fused attention step (fp32, VALU). One block per b.
// t==0: ctx = mean_n img, alphas[:,:,0] = 0.
// t>=1: oh = h @ Wh^T; e[n] = sum_d relu(fvp+oh)*Wa; a = softmax(e);
//       ctx = sum_n a*img; alphas[:,:,t] = a.   ctx -> X[b][512:1024].
// ---------------------------------------------------------------------------
__global__ __launch_bounds__(256) void k_att(float* __restrict__ X,
    const float* __restrict__ Wh, const float* __restrict__ fvp,
    const float* __restrict__ Wa, const float* __restrict__ img,
    float* __restrict__ alph, int t)
{
  const int b = blockIdx.x, tid = threadIdx.x;
  if (t == 0){
    for (int d = tid; d < 512; d += 256){
      float s = 0.f;
      for (int n = 0; n < NN; n++) s += img[((long)b*NN + n)*512 + d];
      X[b*1024 + 512 + d] = s * (1.f/49.f);
    }
    if (tid < NN) alph[((long)b*NN + tid)*TT] = 0.f;
    return;
  }
  __shared__ float hs[512];
  __shared__ float oh[512];
  __shared__ float ee[64];
  for (int d = tid; d < 512; d += 256) hs[d] = X[b*1024 + d];
  __syncthreads();
  for (int d = tid; d < 512; d += 256){
    const float* wr = Wh + (long)d*512;
    float s0=0.f,s1=0.f,s2=0.f,s3=0.f;
    for (int j = 0; j < 512; j += 4){
      s0 = fmaf(hs[j],   wr[j],   s0);
      s1 = fmaf(hs[j+1], wr[j+1], s1);
      s2 = fmaf(hs[j+2], wr[j+2], s2);
      s3 = fmaf(hs[j+3], wr[j+3], s3);
    }
    oh[d] = (s0+s1)+(s2+s3);
  }
  __syncthreads();
  const int w = tid>>6, lane = tid&63;
  for (int n = w; n < NN; n += 4){
    const float* fr = fvp + ((long)b*NN + n)*512;
    float s = 0.f;
    for (int d = lane; d < 512; d += 64)
      s = fmaf(fmaxf(fr[d] + oh[d], 0.f), Wa[d], s);
    #pragma unroll
    for (int off = 32; off; off >>= 1) s += __shfl_xor(s, off);
    if (lane == 0) ee[n] = s;
  }
  __syncthreads();
  if (tid < 64){
    float e = (tid < NN) ? ee[tid] : -1e30f;
    float m = e;
    #pragma unroll
    for (int off = 32; off; off >>= 1) m = fmaxf(m, __shfl_xor(m, off));
    float ex = (tid < NN) ? __expf(e - m) : 0.f;
    float s = ex;
    #pragma unroll
    for (int off = 32; off; off >>= 1) s += __shfl_xor(s, off);
    float a = ex / s;
    if (tid < NN){ ee[tid] = a; alph[((long)b*NN + tid)*TT + t] = a; }
  }
  __syncthreads();
  for (int d = tid; d < 512; d += 256){
    float z = 0.f;
    for (int n = 0; n < NN; n++)
      z = fmaf(ee[n], img[((long)b*NN + n)*512 + d], z);
    X[b*1024 + 512 + d] = z;
  }
}

// ---------------------------------------------------------------------------
// Gates + LSTM cell (fp32, VALU). grid (8 jt, 16 bt) x 256 thr.
// Block: 8 b's x 64 cells; x = [h | ctx | emb] staged in LDS (49 KB).
// gate[q*512+j] = x . [Whh_row | Wih_row]  + b_ih + b_hh ; then cell update.
// ---------------------------------------------------------------------------
__global__ __launch_bounds__(256) void k_gat(const float* __restrict__ Xin,
    const float* __restrict__ Whh, const float* __restrict__ Wih,
    const float* __restrict__ embed, const int* __restrict__ caps,
    const float* __restrict__ bih, const float* __restrict__ bhh,
    float* __restrict__ cst, float* __restrict__ Xout,
    short* __restrict__ Hall, int t)
{
  const int jt = blockIdx.x, bt = blockIdx.y;
  const int b0 = bt*8, J0 = jt*64;
  __shared__ float xs[8][1536];
  const int tid = threadIdx.x;
  for (int i = tid; i < 8*1536; i += 256){
    int bl = i / 1536, k = i - bl*1536;
    int gb = b0 + bl;
    float v;
    if (k < 512)       v = (t == 0) ? 0.f : Xin[gb*1024 + k];
    else if (k < 1024) v = Xin[gb*1024 + k];
    else               v = embed[(long)caps[gb*TT + t]*512 + (k - 1024)];
    xs[bl][k] = v;
  }
  __syncthreads();
  for (int task = tid; task < 512; task += 256){
    int bl = task >> 6, jc = task & 63;
    int gb = b0 + bl, j = J0 + jc;
    float g4[4];
    #pragma unroll
    for (int q = 0; q < 4; q++){
      int row = q*512 + j;
      const float* whr = Whh + (long)row*512;
      const float* wir = Wih + (long)row*1024;
      float s0=0.f,s1=0.f,s2=0.f,s3=0.f;
      for (int k = 0; k < 512; k += 4){
        s0 = fmaf(xs[bl][k],   whr[k],   s0);
        s1 = fmaf(xs[bl][k+1], whr[k+1], s1);
        s2 = fmaf(xs[bl][k+2], whr[k+2], s2);
        s3 = fmaf(xs[bl][k+3], whr[k+3], s3);
      }
      for (int k = 0; k < 1024; k += 4){
        s0 = fmaf(xs[bl][512+k],   wir[k],   s0);
        s1 = fmaf(xs[bl][512+k+1], wir[k+1], s1);
        s2 = fmaf(xs[bl][512+k+2], wir[k+2], s2);
        s3 = fmaf(xs[bl][512+k+3], wir[k+3], s3);
      }
      g4[q] = ((s0+s1)+(s2+s3)) + bih[row] + bhh[row];
    }
    float ii = 1.f/(1.f+__expf(-g4[0]));
    float ff = 1.f/(1.f+__expf(-g4[1]));
    float e2 = __expf(2.f*g4[2]); float gg = (e2-1.f)/(e2+1.f);
    float oo = 1.f/(1.f+__expf(-g4[3]));
    float cp = (t == 0) ? 0.f : cst[gb*512 + j];
    float cN = ff*cp + ii*gg;
    float e3 = __expf(2.f*cN); float th = (e3-1.f)/(e3+1.f);
    float hN = oo*th;
    cst[gb*512 + j] = cN;
    Xout[gb*1024 + j] = hN;
    Hall[((long)gb*TT + t)*512 + j] = f2bf(hN);
  }
}

// ---------------------------------------------------------------------------
// Final GEMM (MFMA, m97-style): preds = Hall(bf16) @ Wout(f32->bf16)^T + bout.
// 128x128 tile, K=512. grid (79, 20) x 256 thr.
// ---------------------------------------------------------------------------
__global__ __launch_bounds__(256) void k_out(const short* __restrict__ Abf,
    const float* __restrict__ Bf32, float* __restrict__ outf,
    const float* __restrict__ bias)
{
  const int n0 = blockIdx.x*128, m0 = blockIdx.y*128;
  __shared__ short As[128*40];
  __shared__ short Bs[128*40];
  const int tid = threadIdx.x, w = tid>>6, lane = tid&63;
  f32x4 acc[8][2] = {};
  for (int k0 = 0; k0 < 512; k0 += 32){
    for (int c = tid; c < 512; c += 256){
      int row = c>>2, ko = (c&3)*8;
      *(s8x8*)(As + row*40 + ko) = *(const s8x8*)(Abf + (long)(m0+row)*512 + k0 + ko);
      int brow = n0 + row;
      s8x8 bv = {0,0,0,0,0,0,0,0};
      if (brow < VV) bv = cast8(Bf32 + (long)brow*512 + k0 + ko);
      *(s8x8*)(Bs + row*40 + ko) = bv;
    }
    __syncthreads();
    const int kb = (lane>>4)*8, l15 = lane&15;
    s8x8 b0f = *(const s8x8*)(Bs + (w*32 + l15)*40 + kb);
    s8x8 b1f = *(const s8x8*)(Bs + (w*32 + 16 + l15)*40 + kb);
    #pragma unroll
    for (int mt = 0; mt < 8; mt++){
      s8x8 a = *(const s8x8*)(As + (mt*16 + l15)*40 + kb);
      acc[mt][0] = mfma16(a, b0f, acc[mt][0]);
      acc[mt][1] = mfma16(a, b1f, acc[mt][1]);
    }
    __syncthreads();
  }
  const int l15 = lane&15;
  #pragma unroll
  for (int mt = 0; mt < 8; mt++){
    int rb = m0 + mt*16 + ((lane>>4)<<2);
    #pragma unroll
    for (int nt = 0; nt < 2; nt++){
      int cg = n0 + w*32 + nt*16 + l15;
      if (cg >= VV) continue;
      #pragma unroll
      for (int rr = 0; rr < 4; rr++){
        int r = rb + rr;
        outf[(long)r*VV + cg] = acc[mt][nt][rr] + bias[cg];
      }
    }
  }
}

// ---------------------------------------------------------------------------
extern "C" void kernel_launch(void* const* d_in, const int* in_sizes, int n_in,
                              void* d_out, int out_size, void* d_ws, size_t ws_size,
                              hipStream_t stream)
{
  const float* img  = (const float*)d_in[0];
  const int*   caps = (const int*)d_in[1];
  const float* emb  = (const float*)d_in[2];
  const float* Wv   = (const float*)d_in[3];
  const float* Wh   = (const float*)d_in[4];
  const float* attb = (const float*)d_in[5];
  const float* Wa   = (const float*)d_in[6];
  const float* Wih  = (const float*)d_in[7];
  const float* bih  = (const float*)d_in[8];
  const float* Whh  = (const float*)d_in[9];
  const float* bhh  = (const float*)d_in[10];
  const float* Wout = (const float*)d_in[11];
  const float* bout = (const float*)d_in[12];
  float* preds = (float*)d_out;
  float* alph  = preds + (long)BB*TT*VV;

  // Workspace layout (16.78 MB total):
  char* ws = (char*)d_ws;
  float* fvp  = (float*)(ws);              // [6272][512] f32 = 12,845,056 B
  float* Xbuf = (float*)(ws + 12845056);   // 2 x [128][1024] f32 = 1,048,576 B
  float* cst  = (float*)(ws + 13893632);   // [128][512] f32 = 262,144 B
  short* Hall = (short*)(ws + 14155776);   // [2560][512] bf16 = 2,621,440 B
                                           // end: 16,777,216 B

  k_fv<<<392, 256, 0, stream>>>(img, Wv, attb, fvp);

  for (int t = 0; t < TT; t++){
    float* Xc = Xbuf + (t&1)*131072;
    float* Xn = Xbuf + ((t+1)&1)*131072;
    k_att<<<128, 256, 0, stream>>>(Xc, Wh, fvp, Wa, img, alph, t);
    k_gat<<<dim3(8,16), 256, 0, stream>>>(Xc, Whh, Wih, emb, caps, bih, bhh,
                                          cst, Xn, Hall, t);
  }

  k_out<<<dim3(79,20), 256, 0, stream>>>(Hall, Wout, preds, bout);
}

// Round 5
// 3552.954 us; speedup vs baseline: 2.2740x; 2.2740x over previous
//
#include <hip/hip_runtime.h>
#include <hip/hip_bf16.h>

#define BB 128
#define NN 49
#define VV 10000
#define TT 20

typedef short s8x8 __attribute__((ext_vector_type(8)));
typedef __bf16 bf8x8 __attribute__((ext_vector_type(8)));
typedef float f32x4 __attribute__((ext_vector_type(4)));

__device__ __forceinline__ short f2bf(float f){ return __builtin_bit_cast(short, (__bf16)f); }

__device__ __forceinline__ s8x8 cast8(const float* p){
  float4 a = *(const float4*)p;
  float4 b = *(const float4*)(p + 4);
  s8x8 r;
  r[0] = f2bf(a.x); r[1] = f2bf(a.y); r[2] = f2bf(a.z); r[3] = f2bf(a.w);
  r[4] = f2bf(b.x); r[5] = f2bf(b.y); r[6] = f2bf(b.z); r[7] = f2bf(b.w);
  return r;
}

__device__ __forceinline__ f32x4 mfma16(s8x8 a, s8x8 b, f32x4 c){
  return __builtin_amdgcn_mfma_f32_16x16x32_bf16(
      __builtin_bit_cast(bf8x8, a), __builtin_bit_cast(bf8x8, b), c, 0, 0, 0);
}

// ---------------------------------------------------------------------------
// fvp = img @ Wv^T + att_b[r%49]  (fp32 out).  Clone of k_out template.
// grid (4, 49): n0 = bx*128 (<=512), m0 = by*128 (<=6272). K=512.
// ---------------------------------------------------------------------------
__global__ __launch_bounds__(256) void k_fv(const float* __restrict__ img,
    const float* __restrict__ Wv, const float* __restrict__ attb,
    float* __restrict__ fvp)
{
  const int n0 = blockIdx.x*128, m0 = blockIdx.y*128;
  __shared__ short As[128*40];
  __shared__ short Bs[128*40];
  const int tid = threadIdx.x, w = tid>>6, lane = tid&63;
  f32x4 acc[8][2] = {};
  for (int k0 = 0; k0 < 512; k0 += 32){
    for (int c = tid; c < 512; c += 256){
      int row = c>>2, ko = (c&3)*8;
      *(s8x8*)(As + row*40 + ko) = cast8(img + (long)(m0+row)*512 + k0 + ko);
      *(s8x8*)(Bs + row*40 + ko) = cast8(Wv  + (long)(n0+row)*512 + k0 + ko);
    }
    __syncthreads();
    const int kb = (lane>>4)*8, l15 = lane&15;
    s8x8 b0f = *(const s8x8*)(Bs + (w*32 + l15)*40 + kb);
    s8x8 b1f = *(const s8x8*)(Bs + (w*32 + 16 + l15)*40 + kb);
    #pragma unroll
    for (int mt = 0; mt < 8; mt++){
      s8x8 a = *(const s8x8*)(As + (mt*16 + l15)*40 + kb);
      acc[mt][0] = mfma16(a, b0f, acc[mt][0]);
      acc[mt][1] = mfma16(a, b1f, acc[mt][1]);
    }
    __syncthreads();
  }
  const int l15 = lane&15;
  #pragma unroll
  for (int mt = 0; mt < 8; mt++){
    int rb = m0 + mt*16 + ((lane>>4)<<2);
    #pragma unroll
    for (int nt = 0; nt < 2; nt++){
      int cg = n0 + w*32 + nt*16 + l15;
      #pragma unroll
      for (int rr = 0; rr < 4; rr++){
        int r = rb + rr;
        fvp[(long)r*512 + cg] = acc[mt][nt][rr] + attb[r % NN];
      }
    }
  }
}

// ---------------------------------------------------------------------------
// Fused attention step (fp32, VALU). One block per b.  (unchanged, verified)
// ---------------------------------------------------------------------------
__global__ __launch_bounds__(256) void k_att(float* __restrict__ X,
    const float* __restrict__ Wh, const float* __restrict__ fvp,
    const float* __restrict__ Wa, const float* __restrict__ img,
    float* __restrict__ alph, int t)
{
  const int b = blockIdx.x, tid = threadIdx.x;
  if (t == 0){
    for (int d = tid; d < 512; d += 256){
      float s = 0.f;
      for (int n = 0; n < NN; n++) s += img[((long)b*NN + n)*512 + d];
      X[b*1024 + 512 + d] = s * (1.f/49.f);
    }
    if (tid < NN) alph[((long)b*NN + tid)*TT] = 0.f;
    return;
  }
  __shared__ float hs[512];
  __shared__ float oh[512];
  __shared__ float ee[64];
  for (int d = tid; d < 512; d += 256) hs[d] = X[b*1024 + d];
  __syncthreads();
  for (int d = tid; d < 512; d += 256){
    const float* wr = Wh + (long)d*512;
    float s0=0.f,s1=0.f,s2=0.f,s3=0.f;
    for (int j = 0; j < 512; j += 4){
      s0 = fmaf(hs[j],   wr[j],   s0);
      s1 = fmaf(hs[j+1], wr[j+1], s1);
      s2 = fmaf(hs[j+2], wr[j+2], s2);
      s3 = fmaf(hs[j+3], wr[j+3], s3);
    }
    oh[d] = (s0+s1)+(s2+s3);
  }
  __syncthreads();
  const int w = tid>>6, lane = tid&63;
  for (int n = w; n < NN; n += 4){
    const float* fr = fvp + ((long)b*NN + n)*512;
    float s = 0.f;
    for (int d = lane; d < 512; d += 64)
      s = fmaf(fmaxf(fr[d] + oh[d], 0.f), Wa[d], s);
    #pragma unroll
    for (int off = 32; off; off >>= 1) s += __shfl_xor(s, off);
    if (lane == 0) ee[n] = s;
  }
  __syncthreads();
  if (tid < 64){
    float e = (tid < NN) ? ee[tid] : -1e30f;
    float m = e;
    #pragma unroll
    for (int off = 32; off; off >>= 1) m = fmaxf(m, __shfl_xor(m, off));
    float ex = (tid < NN) ? __expf(e - m) : 0.f;
    float s = ex;
    #pragma unroll
    for (int off = 32; off; off >>= 1) s += __shfl_xor(s, off);
    float a = ex / s;
    if (tid < NN){ ee[tid] = a; alph[((long)b*NN + tid)*TT + t] = a; }
  }
  __syncthreads();
  for (int d = tid; d < 512; d += 256){
    float z = 0.f;
    for (int n = 0; n < NN; n++)
      z = fmaf(ee[n], img[((long)b*NN + n)*512 + d], z);
    X[b*1024 + 512 + d] = z;
  }
}

// ---------------------------------------------------------------------------
// Gates + LSTM cell via MFMA (k_out-template clone).
// grid (16, 2): J0 = bx*32 cells, b0 = by*64 batches. M=64, N=128(packed:
// tile col = q*32+jc -> weight row jg = q*512+J0+jc), K=1536 = [h|ctx|emb].
// Epilogue: acc -> LDS gs[64][132] -> fused LSTM cell, h -> Xout & Hall.
// ---------------------------------------------------------------------------
__global__ __launch_bounds__(256) void k_gat(const float* __restrict__ Xin,
    const float* __restrict__ Whh, const float* __restrict__ Wih,
    const float* __restrict__ embed, const int* __restrict__ caps,
    const float* __restrict__ bih, const float* __restrict__ bhh,
    float* __restrict__ cst, float* __restrict__ Xout,
    short* __restrict__ Hall, int t)
{
  const int J0 = blockIdx.x*32, b0 = blockIdx.y*64;
  __shared__ short As[64*40];
  __shared__ short Bs[128*40];
  __shared__ float gs[64][132];
  const int tid = threadIdx.x, w = tid>>6, lane = tid&63;
  f32x4 acc[4][2] = {};
  for (int k0 = 0; k0 < 1536; k0 += 32){
    {
      // A: 64 batch rows x 32 k. 256 chunks, one per thread.
      int row = tid>>2, ko = (tid&3)*8;
      int gb = b0 + row, k = k0 + ko;
      s8x8 av = {0,0,0,0,0,0,0,0};
      if (k0 < 1024){
        if (!(t == 0 && k0 < 512))
          av = cast8(Xin + (long)gb*1024 + k);
      } else {
        int cap = caps[gb*TT + t];
        av = cast8(embed + (long)cap*512 + (k - 1024));
      }
      *(s8x8*)(As + row*40 + ko) = av;
    }
    for (int c = tid; c < 512; c += 256){
      // B: 128 packed gate rows x 32 k.
      int row = c>>2, ko = (c&3)*8;
      int jg = ((row>>5)<<9) + J0 + (row&31);
      int k = k0 + ko;
      s8x8 bv = (k0 < 512) ? cast8(Whh + (long)jg*512 + k)
                           : cast8(Wih + (long)jg*1024 + (k - 512));
      *(s8x8*)(Bs + row*40 + ko) = bv;
    }
    __syncthreads();
    const int kb = (lane>>4)*8, l15 = lane&15;
    s8x8 b0f = *(const s8x8*)(Bs + (w*32 + l15)*40 + kb);
    s8x8 b1f = *(const s8x8*)(Bs + (w*32 + 16 + l15)*40 + kb);
    #pragma unroll
    for (int mt = 0; mt < 4; mt++){
      s8x8 a = *(const s8x8*)(As + (mt*16 + l15)*40 + kb);
      acc[mt][0] = mfma16(a, b0f, acc[mt][0]);
      acc[mt][1] = mfma16(a, b1f, acc[mt][1]);
    }
    __syncthreads();
  }
  {
    const int l15 = lane&15;
    #pragma unroll
    for (int mt = 0; mt < 4; mt++){
      int rl = mt*16 + ((lane>>4)<<2);
      #pragma unroll
      for (int nt = 0; nt < 2; nt++){
        int ct = w*32 + nt*16 + l15;
        #pragma unroll
        for (int rr = 0; rr < 4; rr++)
          gs[rl+rr][ct] = acc[mt][nt][rr];
      }
    }
  }
  __syncthreads();
  for (int task = tid; task < 2048; task += 256){
    int bl = task>>5, jc = task&31;
    int gb = b0 + bl, j = J0 + jc;
    float gi = gs[bl][jc]    + bih[j]      + bhh[j];
    float gf = gs[bl][32+jc] + bih[512+j]  + bhh[512+j];
    float gg = gs[bl][64+jc] + bih[1024+j] + bhh[1024+j];
    float go = gs[bl][96+jc] + bih[1536+j] + bhh[1536+j];
    float ii = 1.f/(1.f+__expf(-gi));
    float ff = 1.f/(1.f+__expf(-gf));
    float e2 = __expf(2.f*gg); float g2 = (e2-1.f)/(e2+1.f);
    float oo = 1.f/(1.f+__expf(-go));
    float cp = (t == 0) ? 0.f : cst[gb*512 + j];
    float cN = ff*cp + ii*g2;
    float e3 = __expf(2.f*cN); float th = (e3-1.f)/(e3+1.f);
    float hN = oo*th;
    cst[gb*512 + j] = cN;
    Xout[gb*1024 + j] = hN;
    Hall[((long)gb*TT + t)*512 + j] = f2bf(hN);
  }
}

// ---------------------------------------------------------------------------
// Final GEMM: preds = Hall(bf16) @ Wout(f32->bf16)^T + bout.  (unchanged)
// ---------------------------------------------------------------------------
__global__ __launch_bounds__(256) void k_out(const short* __restrict__ Abf,
    const float* __restrict__ Bf32, float* __restrict__ outf,
    const float* __restrict__ bias)
{
  const int n0 = blockIdx.x*128, m0 = blockIdx.y*128;
  __shared__ short As[128*40];
  __shared__ short Bs[128*40];
  const int tid = threadIdx.x, w = tid>>6, lane = tid&63;
  f32x4 acc[8][2] = {};
  for (int k0 = 0; k0 < 512; k0 += 32){
    for (int c = tid; c < 512; c += 256){
      int row = c>>2, ko = (c&3)*8;
      *(s8x8*)(As + row*40 + ko) = *(const s8x8*)(Abf + (long)(m0+row)*512 + k0 + ko);
      int brow = n0 + row;
      s8x8 bv = {0,0,0,0,0,0,0,0};
      if (brow < VV) bv = cast8(Bf32 + (long)brow*512 + k0 + ko);
      *(s8x8*)(Bs + row*40 + ko) = bv;
    }
    __syncthreads();
    const int kb = (lane>>4)*8, l15 = lane&15;
    s8x8 b0f = *(const s8x8*)(Bs + (w*32 + l15)*40 + kb);
    s8x8 b1f = *(const s8x8*)(Bs + (w*32 + 16 + l15)*40 + kb);
    #pragma unroll
    for (int mt = 0; mt < 8; mt++){
      s8x8 a = *(const s8x8*)(As + (mt*16 + l15)*40 + kb);
      acc[mt][0] = mfma16(a, b0f, acc[mt][0]);
      acc[mt][1] = mfma16(a, b1f, acc[mt][1]);
    }
    __syncthreads();
  }
  const int l15 = lane&15;
  #pragma unroll
  for (int mt = 0; mt < 8; mt++){
    int rb = m0 + mt*16 + ((lane>>4)<<2);
    #pragma unroll
    for (int nt = 0; nt < 2; nt++){
      int cg = n0 + w*32 + nt*16 + l15;
      if (cg >= VV) continue;
      #pragma unroll
      for (int rr = 0; rr < 4; rr++){
        int r = rb + rr;
        outf[(long)r*VV + cg] = acc[mt][nt][rr] + bias[cg];
      }
    }
  }
}

// ---------------------------------------------------------------------------
extern "C" void kernel_launch(void* const* d_in, const int* in_sizes, int n_in,
                              void* d_out, int out_size, void* d_ws, size_t ws_size,
                              hipStream_t stream)
{
  const float* img  = (const float*)d_in[0];
  const int*   caps = (const int*)d_in[1];
  const float* emb  = (const float*)d_in[2];
  const float* Wv   = (const float*)d_in[3];
  const float* Wh   = (const float*)d_in[4];
  const float* attb = (const float*)d_in[5];
  const float* Wa   = (const float*)d_in[6];
  const float* Wih  = (const float*)d_in[7];
  const float* bih  = (const float*)d_in[8];
  const float* Whh  = (const float*)d_in[9];
  const float* bhh  = (const float*)d_in[10];
  const float* Wout = (const float*)d_in[11];
  const float* bout = (const float*)d_in[12];
  float* preds = (float*)d_out;
  float* alph  = preds + (long)BB*TT*VV;

  // Workspace layout (16.78 MB total, proven available):
  char* ws = (char*)d_ws;
  float* fvp  = (float*)(ws);              // [6272][512] f32 = 12,845,056 B
  float* Xbuf = (float*)(ws + 12845056);   // 2 x [128][1024] f32 = 1,048,576 B
  float* cst  = (float*)(ws + 13893632);   // [128][512] f32 = 262,144 B
  short* Hall = (short*)(ws + 14155776);   // [2560][512] bf16 = 2,621,440 B
                                           // end: 16,777,216 B

  k_fv<<<dim3(4,49), 256, 0, stream>>>(img, Wv, attb, fvp);

  for (int t = 0; t < TT; t++){
    float* Xc = Xbuf + (t&1)*131072;
    float* Xn = Xbuf + ((t+1)&1)*131072;
    k_att<<<128, 256, 0, stream>>>(Xc, Wh, fvp, Wa, img, alph, t);
    k_gat<<<dim3(16,2), 256, 0, stream>>>(Xc, Whh, Wih, emb, caps, bih, bhh,
                                          cst, Xn, Hall, t);
  }

  k_out<<<dim3(79,20), 256, 0, stream>>>(Hall, Wout, preds, bout);
}

// Round 6
// 1133.173 us; speedup vs baseline: 7.1298x; 3.1354x over previous
//
#include <hip/hip_runtime.h>
#include <hip/hip_bf16.h>

#define BB 128
#define NN 49
#define VV 10000
#define TT 20

typedef short s8x8 __attribute__((ext_vector_type(8)));
typedef __bf16 bf8x8 __attribute__((ext_vector_type(8)));
typedef float f32x4 __attribute__((ext_vector_type(4)));

__device__ __forceinline__ float bf2f(short s){ return (float)__builtin_bit_cast(__bf16, s); }
__device__ __forceinline__ short f2bf(float f){ return __builtin_bit_cast(short, (__bf16)f); }

__device__ __forceinline__ s8x8 cast8(const float* p){
  float4 a = *(const float4*)p;
  float4 b = *(const float4*)(p + 4);
  s8x8 r;
  r[0] = f2bf(a.x); r[1] = f2bf(a.y); r[2] = f2bf(a.z); r[3] = f2bf(a.w);
  r[4] = f2bf(b.x); r[5] = f2bf(b.y); r[6] = f2bf(b.z); r[7] = f2bf(b.w);
  return r;
}

__device__ __forceinline__ f32x4 mfma16(s8x8 a, s8x8 b, f32x4 c){
  return __builtin_amdgcn_mfma_f32_16x16x32_bf16(
      __builtin_bit_cast(bf8x8, a), __builtin_bit_cast(bf8x8, b), c, 0, 0, 0);
}

// ---------------------------------------------------------------------------
// One-time prepack: wcatp = gate-packed bf16 weights in k_gat streaming order
//   wcatp[((jt*24 + it)*128 + row)*64 + kk], row=packed(q,jc): jg=q*512+jt*32+jc
//   k = it*64+kk; k<512 -> Whh[jg][k], else Wih[jg][k-512]
// whp = bf16 Wh [512][512].
// ---------------------------------------------------------------------------
__global__ __launch_bounds__(256) void k_prep2(
    const float* __restrict__ Whh, const float* __restrict__ Wih,
    const float* __restrict__ Wh,
    short* __restrict__ wcatp, short* __restrict__ whp)
{
  const long CW = 393216;  // 2048*1536/8
  const long CH = 32768;   // 512*512/8
  for (long c = blockIdx.x*256L + threadIdx.x; c < CW + CH; c += (long)gridDim.x*256L){
    if (c < CW){
      long s = c*8;
      int jt = (int)(s / 196608);
      int r  = (int)(s % 196608);
      int it = r >> 13;
      int r2 = r & 8191;
      int row = r2 >> 6, kk = r2 & 63;
      int jg = ((row>>5)<<9) + jt*32 + (row&31);
      int k = it*64 + kk;
      const float* src = (k < 512) ? (Whh + (long)jg*512 + k)
                                   : (Wih + (long)jg*1024 + (k - 512));
      *(s8x8*)(wcatp + s) = cast8(src);
    } else {
      long j = (c - CW)*8;
      *(s8x8*)(whp + j) = cast8(Wh + j);
    }
  }
}

// ---------------------------------------------------------------------------
// Late prepack (after t-loop; aliases dead wcatp/fvbf region): Wout -> bf16.
// ---------------------------------------------------------------------------
__global__ __launch_bounds__(256) void k_packout(const float* __restrict__ Wout,
                                                 short* __restrict__ woutbf)
{
  for (long c = blockIdx.x*256L + threadIdx.x; c < 640000; c += (long)gridDim.x*256L)
    *(s8x8*)(woutbf + c*8) = cast8(Wout + c*8);
}

// ---------------------------------------------------------------------------
// fvp = img @ Wv^T + att_b[r%49]  (bf16 out). Proven 128x128 template.
// grid (4, 49). K=512, fp32 sources inline-cast (runs once).
// ---------------------------------------------------------------------------
__global__ __launch_bounds__(256) void k_fv(const float* __restrict__ img,
    const float* __restrict__ Wv, const float* __restrict__ attb,
    short* __restrict__ fvbf)
{
  const int n0 = blockIdx.x*128, m0 = blockIdx.y*128;
  __shared__ short As[128*40];
  __shared__ short Bs[128*40];
  const int tid = threadIdx.x, w = tid>>6, lane = tid&63;
  f32x4 acc[8][2] = {};
  for (int k0 = 0; k0 < 512; k0 += 32){
    for (int c = tid; c < 512; c += 256){
      int row = c>>2, ko = (c&3)*8;
      *(s8x8*)(As + row*40 + ko) = cast8(img + (long)(m0+row)*512 + k0 + ko);
      *(s8x8*)(Bs + row*40 + ko) = cast8(Wv  + (long)(n0+row)*512 + k0 + ko);
    }
    __syncthreads();
    const int kb = (lane>>4)*8, l15 = lane&15;
    s8x8 b0f = *(const s8x8*)(Bs + (w*32 + l15)*40 + kb);
    s8x8 b1f = *(const s8x8*)(Bs + (w*32 + 16 + l15)*40 + kb);
    #pragma unroll
    for (int mt = 0; mt < 8; mt++){
      s8x8 a = *(const s8x8*)(As + (mt*16 + l15)*40 + kb);
      acc[mt][0] = mfma16(a, b0f, acc[mt][0]);
      acc[mt][1] = mfma16(a, b1f, acc[mt][1]);
    }
    __syncthreads();
  }
  const int l15 = lane&15;
  #pragma unroll
  for (int mt = 0; mt < 8; mt++){
    int rb = m0 + mt*16 + ((lane>>4)<<2);
    #pragma unroll
    for (int nt = 0; nt < 2; nt++){
      int cg = n0 + w*32 + nt*16 + l15;
      #pragma unroll
      for (int rr = 0; rr < 4; rr++){
        int r = rb + rr;
        fvbf[(long)r*512 + cg] = f2bf(acc[mt][nt][rr] + attb[r % NN]);
      }
    }
  }
}

// ---------------------------------------------------------------------------
// ohall = h_{t-1} @ Wh^T  (f32 out). Proven template, M=128, N=512, K=512.
// grid (4,1). A = Hcur bf16 [128][512], B = whp bf16.
// ---------------------------------------------------------------------------
__global__ __launch_bounds__(256) void k_oh(const short* __restrict__ Hcur,
    const short* __restrict__ whp, float* __restrict__ ohall)
{
  const int n0 = blockIdx.x*128;
  __shared__ short As[128*40];
  __shared__ short Bs[128*40];
  const int tid = threadIdx.x, w = tid>>6, lane = tid&63;
  f32x4 acc[8][2] = {};
  for (int k0 = 0; k0 < 512; k0 += 32){
    for (int c = tid; c < 512; c += 256){
      int row = c>>2, ko = (c&3)*8;
      *(s8x8*)(As + row*40 + ko) = *(const s8x8*)(Hcur + (long)row*512 + k0 + ko);
      *(s8x8*)(Bs + row*40 + ko) = *(const s8x8*)(whp + (long)(n0+row)*512 + k0 + ko);
    }
    __syncthreads();
    const int kb = (lane>>4)*8, l15 = lane&15;
    s8x8 b0f = *(const s8x8*)(Bs + (w*32 + l15)*40 + kb);
    s8x8 b1f = *(const s8x8*)(Bs + (w*32 + 16 + l15)*40 + kb);
    #pragma unroll
    for (int mt = 0; mt < 8; mt++){
      s8x8 a = *(const s8x8*)(As + (mt*16 + l15)*40 + kb);
      acc[mt][0] = mfma16(a, b0f, acc[mt][0]);
      acc[mt][1] = mfma16(a, b1f, acc[mt][1]);
    }
    __syncthreads();
  }
  const int l15 = lane&15;
  #pragma unroll
  for (int mt = 0; mt < 8; mt++){
    int rb = mt*16 + ((lane>>4)<<2);
    #pragma unroll
    for (int nt = 0; nt < 2; nt++){
      int cg = n0 + w*32 + nt*16 + l15;
      #pragma unroll
      for (int rr = 0; rr < 4; rr++)
        ohall[(long)(rb+rr)*512 + cg] = acc[mt][nt][rr];
    }
  }
}

// ---------------------------------------------------------------------------
// Attention: e = sum_d relu(fvbf + oh)*Wa; softmax; ctx = sum_n a*img -> Cbuf.
// t==0: ctx = mean_n img; alphas = 0. One block per b.
// ---------------------------------------------------------------------------
__global__ __launch_bounds__(256) void k_att(const float* __restrict__ ohall,
    const short* __restrict__ fvbf, const float* __restrict__ Wa,
    const float* __restrict__ img, short* __restrict__ Cbuf,
    float* __restrict__ alph, int t)
{
  const int b = blockIdx.x, tid = threadIdx.x;
  if (t == 0){
    for (int d = tid; d < 512; d += 256){
      float s = 0.f;
      for (int n = 0; n < NN; n++) s += img[((long)b*NN + n)*512 + d];
      Cbuf[b*512 + d] = f2bf(s * (1.f/49.f));
    }
    if (tid < NN) alph[((long)b*NN + tid)*TT] = 0.f;
    return;
  }
  __shared__ float ee[64];
  __shared__ float zp[4][512];
  const int w = tid>>6, lane = tid&63;
  float ohr[8], war[8];
  {
    const float* op = ohall + b*512 + lane*8;
    const float* wp = Wa + lane*8;
    #pragma unroll
    for (int q = 0; q < 8; q++){ ohr[q] = op[q]; war[q] = wp[q]; }
  }
  for (int n = w; n < NN; n += 4){
    s8x8 v = *(const s8x8*)(fvbf + ((long)b*NN + n)*512 + lane*8);
    float s = 0.f;
    #pragma unroll
    for (int q = 0; q < 8; q++)
      s = fmaf(fmaxf(bf2f(v[q]) + ohr[q], 0.f), war[q], s);
    #pragma unroll
    for (int off = 32; off; off >>= 1) s += __shfl_xor(s, off);
    if (lane == 0) ee[n] = s;
  }
  __syncthreads();
  if (tid < 64){
    float e = (tid < NN) ? ee[tid] : -1e30f;
    float m = e;
    #pragma unroll
    for (int off = 32; off; off >>= 1) m = fmaxf(m, __shfl_xor(m, off));
    float ex = (tid < NN) ? __expf(e - m) : 0.f;
    float s = ex;
    #pragma unroll
    for (int off = 32; off; off >>= 1) s += __shfl_xor(s, off);
    float a = ex / s;
    if (tid < NN){ ee[tid] = a; alph[((long)b*NN + tid)*TT + t] = a; }
  }
  __syncthreads();
  const int cq = tid>>6, d0 = (tid&63)*8;
  float z[8] = {0,0,0,0,0,0,0,0};
  for (int n = cq; n < NN; n += 4){
    float an = ee[n];
    const float* ip = img + ((long)b*NN + n)*512 + d0;
    float4 u0 = *(const float4*)ip;
    float4 u1 = *(const float4*)(ip + 4);
    z[0] = fmaf(an, u0.x, z[0]); z[1] = fmaf(an, u0.y, z[1]);
    z[2] = fmaf(an, u0.z, z[2]); z[3] = fmaf(an, u0.w, z[3]);
    z[4] = fmaf(an, u1.x, z[4]); z[5] = fmaf(an, u1.y, z[5]);
    z[6] = fmaf(an, u1.z, z[6]); z[7] = fmaf(an, u1.w, z[7]);
  }
  #pragma unroll
  for (int q = 0; q < 8; q++) zp[cq][d0 + q] = z[q];
  __syncthreads();
  if (tid < 64){
    int dd = tid*8;
    s8x8 o;
    #pragma unroll
    for (int q = 0; q < 8; q++)
      o[q] = f2bf(zp[0][dd+q] + zp[1][dd+q] + zp[2][dd+q] + zp[3][dd+q]);
    *(s8x8*)(Cbuf + b*512 + dd) = o;
  }
}

// ---------------------------------------------------------------------------
// Gates + LSTM cell. grid (16 jt, 2 bt). M=64 batch rows, N=128 packed gate
// cols (q*32+jc), K=1536 = [h(Hcur) | ctx(Cbuf) | emb(inline-cast gather)].
// BK=64, register-prefetch pipeline, B-stream fully linear from wcatp.
// ---------------------------------------------------------------------------
__global__ __launch_bounds__(256) void k_gat(const short* __restrict__ Hcur,
    const short* __restrict__ Cbuf, const short* __restrict__ wcatp,
    const float* __restrict__ embed, const int* __restrict__ caps,
    const float* __restrict__ bih, const float* __restrict__ bhh,
    float* __restrict__ cst, short* __restrict__ Hnxt,
    short* __restrict__ Hall, int t)
{
  const int jt = blockIdx.x, b0 = blockIdx.y*64;
  const int J0 = jt*32;
  __shared__ short As[64*76];
  __shared__ short Bs[128*76];
  __shared__ float gs[64][132];
  const int tid = threadIdx.x, w = tid>>6, lane = tid&63;
  const long wbase = (long)jt*24*8192;

  s8x8 a_r[2], b_r[4];
  auto stage_load = [&](int it){
    #pragma unroll
    for (int i = 0; i < 2; i++){
      int c = tid + i*256;
      int row = c>>3, kkc = (c&7)*8;
      int k = it*64 + kkc, gb = b0 + row;
      s8x8 av = {0,0,0,0,0,0,0,0};
      if (k < 512){
        if (t != 0) av = *(const s8x8*)(Hcur + (long)gb*512 + k);
      } else if (k < 1024){
        av = *(const s8x8*)(Cbuf + (long)gb*512 + (k - 512));
      } else {
        av = cast8(embed + (long)caps[gb*TT + t]*512 + (k - 1024));
      }
      a_r[i] = av;
    }
    #pragma unroll
    for (int i = 0; i < 4; i++){
      long c = tid + i*256;
      b_r[i] = *(const s8x8*)(wcatp + wbase + (long)it*8192 + c*8);
    }
  };

  f32x4 acc[4][2] = {};
  stage_load(0);
  for (int it = 0; it < 24; ++it){
    #pragma unroll
    for (int i = 0; i < 2; i++){
      int c = tid + i*256;
      *(s8x8*)(As + (c>>3)*76 + (c&7)*8) = a_r[i];
    }
    #pragma unroll
    for (int i = 0; i < 4; i++){
      int c = tid + i*256;
      *(s8x8*)(Bs + (c>>3)*76 + (c&7)*8) = b_r[i];
    }
    __syncthreads();
    if (it < 23) stage_load(it + 1);
    const int kb = (lane>>4)*8, l15 = lane&15, cw = w*32;
    #pragma unroll
    for (int ks = 0; ks < 2; ks++){
      s8x8 b0f = *(const s8x8*)(Bs + (cw + l15)*76 + kb + ks*32);
      s8x8 b1f = *(const s8x8*)(Bs + (cw + 16 + l15)*76 + kb + ks*32);
      #pragma unroll
      for (int mt = 0; mt < 4; mt++){
        s8x8 a = *(const s8x8*)(As + (mt*16 + l15)*76 + kb + ks*32);
        acc[mt][0] = mfma16(a, b0f, acc[mt][0]);
        acc[mt][1] = mfma16(a, b1f, acc[mt][1]);
      }
    }
    __syncthreads();
  }
  {
    const int l15 = lane&15;
    #pragma unroll
    for (int mt = 0; mt < 4; mt++){
      int rl = mt*16 + ((lane>>4)<<2);
      #pragma unroll
      for (int nt = 0; nt < 2; nt++){
        int ct = w*32 + nt*16 + l15;
        #pragma unroll
        for (int rr = 0; rr < 4; rr++)
          gs[rl+rr][ct] = acc[mt][nt][rr];
      }
    }
  }
  __syncthreads();
  for (int task = tid; task < 2048; task += 256){
    int bl = task>>5, jc = task&31;
    int gb = b0 + bl, j = J0 + jc;
    float gi = gs[bl][jc]      + bih[j]        + bhh[j];
    float gf = gs[bl][32+jc]   + bih[512+j]    + bhh[512+j];
    float gg = gs[bl][64+jc]   + bih[1024+j]   + bhh[1024+j];
    float go = gs[bl][96+jc]   + bih[1536+j]   + bhh[1536+j];
    float ii = 1.f/(1.f+__expf(-gi));
    float ff = 1.f/(1.f+__expf(-gf));
    float e2 = __expf(2.f*gg); float g2 = (e2-1.f)/(e2+1.f);
    float oo = 1.f/(1.f+__expf(-go));
    float cp = (t == 0) ? 0.f : cst[gb*512 + j];
    float cN = ff*cp + ii*g2;
    float e3 = __expf(2.f*cN); float th = (e3-1.f)/(e3+1.f);
    float hN = oo*th;
    cst[gb*512 + j] = cN;
    short hb = f2bf(hN);
    Hnxt[gb*512 + j] = hb;
    Hall[((long)gb*TT + t)*512 + j] = hb;
  }
}

// ---------------------------------------------------------------------------
// Final GEMM: preds = Hall(bf16) @ woutbf(bf16)^T + bout. Proven template.
// ---------------------------------------------------------------------------
__global__ __launch_bounds__(256) void k_out(const short* __restrict__ Abf,
    const short* __restrict__ Bbf, float* __restrict__ outf,
    const float* __restrict__ bias)
{
  const int n0 = blockIdx.x*128, m0 = blockIdx.y*128;
  __shared__ short As[128*40];
  __shared__ short Bs[128*40];
  const int tid = threadIdx.x, w = tid>>6, lane = tid&63;
  f32x4 acc[8][2] = {};
  for (int k0 = 0; k0 < 512; k0 += 32){
    for (int c = tid; c < 512; c += 256){
      int row = c>>2, ko = (c&3)*8;
      *(s8x8*)(As + row*40 + ko) = *(const s8x8*)(Abf + (long)(m0+row)*512 + k0 + ko);
      int brow = n0 + row;
      s8x8 bv = {0,0,0,0,0,0,0,0};
      if (brow < VV) bv = *(const s8x8*)(Bbf + (long)brow*512 + k0 + ko);
      *(s8x8*)(Bs + row*40 + ko) = bv;
    }
    __syncthreads();
    const int kb = (lane>>4)*8, l15 = lane&15;
    s8x8 b0f = *(const s8x8*)(Bs + (w*32 + l15)*40 + kb);
    s8x8 b1f = *(const s8x8*)(Bs + (w*32 + 16 + l15)*40 + kb);
    #pragma unroll
    for (int mt = 0; mt < 8; mt++){
      s8x8 a = *(const s8x8*)(As + (mt*16 + l15)*40 + kb);
      acc[mt][0] = mfma16(a, b0f, acc[mt][0]);
      acc[mt][1] = mfma16(a, b1f, acc[mt][1]);
    }
    __syncthreads();
  }
  const int l15 = lane&15;
  #pragma unroll
  for (int mt = 0; mt < 8; mt++){
    int rb = m0 + mt*16 + ((lane>>4)<<2);
    #pragma unroll
    for (int nt = 0; nt < 2; nt++){
      int cg = n0 + w*32 + nt*16 + l15;
      if (cg >= VV) continue;
      #pragma unroll
      for (int rr = 0; rr < 4; rr++){
        int r = rb + rr;
        outf[(long)r*VV + cg] = acc[mt][nt][rr] + bias[cg];
      }
    }
  }
}

// ---------------------------------------------------------------------------
extern "C" void kernel_launch(void* const* d_in, const int* in_sizes, int n_in,
                              void* d_out, int out_size, void* d_ws, size_t ws_size,
                              hipStream_t stream)
{
  const float* img  = (const float*)d_in[0];
  const int*   caps = (const int*)d_in[1];
  const float* emb  = (const float*)d_in[2];
  const float* Wv   = (const float*)d_in[3];
  const float* Wh   = (const float*)d_in[4];
  const float* attb = (const float*)d_in[5];
  const float* Wa   = (const float*)d_in[6];
  const float* Wih  = (const float*)d_in[7];
  const float* bih  = (const float*)d_in[8];
  const float* Whh  = (const float*)d_in[9];
  const float* bhh  = (const float*)d_in[10];
  const float* Wout = (const float*)d_in[11];
  const float* bout = (const float*)d_in[12];
  float* preds = (float*)d_out;
  float* alph  = preds + (long)BB*TT*VV;

  // Workspace layout: exactly 16,777,216 B (proven available in R4/R5).
  char* ws = (char*)d_ws;
  short* wcatp  = (short*)(ws);              // 6,291,456 B
  short* whp    = (short*)(ws + 6291456);    //   524,288 B
  short* fvbf   = (short*)(ws + 6815744);    // 6,422,528 B
  short* Hbuf   = (short*)(ws + 13238272);   //   262,144 B (2 x [128][512] bf16)
  short* Cbuf   = (short*)(ws + 13500416);   //   131,072 B
  float* cst    = (float*)(ws + 13631488);   //   262,144 B
  short* Hall   = (short*)(ws + 13893632);   // 2,621,440 B
  float* ohall  = (float*)(ws + 16515072);   //   262,144 B  -> end 16,777,216
  short* woutbf = (short*)(ws);              // alias over wcatp/whp/fvbf (dead
                                             // after t-loop); 10,240,000 B

  k_prep2<<<1024, 256, 0, stream>>>(Whh, Wih, Wh, wcatp, whp);
  k_fv<<<dim3(4,49), 256, 0, stream>>>(img, Wv, attb, fvbf);

  for (int t = 0; t < TT; t++){
    short* Hc = Hbuf + (t&1)*65536;
    short* Hn = Hbuf + ((t+1)&1)*65536;
    if (t > 0)
      k_oh<<<dim3(4,1), 256, 0, stream>>>(Hc, whp, ohall);
    k_att<<<128, 256, 0, stream>>>(ohall, fvbf, Wa, img, Cbuf, alph, t);
    k_gat<<<dim3(16,2), 256, 0, stream>>>(Hc, Cbuf, wcatp, emb, caps, bih, bhh,
                                          cst, Hn, Hall, t);
  }

  k_packout<<<1024, 256, 0, stream>>>(Wout, woutbf);
  k_out<<<dim3(79,20), 256, 0, stream>>>(Hall, woutbf, preds, bout);
}

// Round 7
// 974.142 us; speedup vs baseline: 8.2937x; 1.1633x over previous
//
#include <hip/hip_runtime.h>
#include <hip/hip_bf16.h>

#define BB 128
#define NN 49
#define VV 10000
#define TT 20

typedef short s8x8 __attribute__((ext_vector_type(8)));
typedef __bf16 bf8x8 __attribute__((ext_vector_type(8)));
typedef float f32x4 __attribute__((ext_vector_type(4)));

__device__ __forceinline__ float bf2f(short s){ return (float)__builtin_bit_cast(__bf16, s); }
__device__ __forceinline__ short f2bf(float f){ return __builtin_bit_cast(short, (__bf16)f); }

__device__ __forceinline__ s8x8 cast8(const float* p){
  float4 a = *(const float4*)p;
  float4 b = *(const float4*)(p + 4);
  s8x8 r;
  r[0] = f2bf(a.x); r[1] = f2bf(a.y); r[2] = f2bf(a.z); r[3] = f2bf(a.w);
  r[4] = f2bf(b.x); r[5] = f2bf(b.y); r[6] = f2bf(b.z); r[7] = f2bf(b.w);
  return r;
}

__device__ __forceinline__ f32x4 mfma16(s8x8 a, s8x8 b, f32x4 c){
  return __builtin_amdgcn_mfma_f32_16x16x32_bf16(
      __builtin_bit_cast(bf8x8, a), __builtin_bit_cast(bf8x8, b), c, 0, 0, 0);
}

// ---------------------------------------------------------------------------
// One-time prepack: wcatp = gate-packed bf16 weights in k_gat streaming order
//   wcatp[((jt*24 + it)*128 + row)*64 + kk], row=packed(q,jc): jg=q*512+jt*32+jc
//   k = it*64+kk; k<512 -> Whh[jg][k], else Wih[jg][k-512]
// whp = bf16 Wh [512][512].
// ---------------------------------------------------------------------------
__global__ __launch_bounds__(256) void k_prep2(
    const float* __restrict__ Whh, const float* __restrict__ Wih,
    const float* __restrict__ Wh,
    short* __restrict__ wcatp, short* __restrict__ whp)
{
  const long CW = 393216;  // 2048*1536/8
  const long CH = 32768;   // 512*512/8
  for (long c = blockIdx.x*256L + threadIdx.x; c < CW + CH; c += (long)gridDim.x*256L){
    if (c < CW){
      long s = c*8;
      int jt = (int)(s / 196608);
      int r  = (int)(s % 196608);
      int it = r >> 13;
      int r2 = r & 8191;
      int row = r2 >> 6, kk = r2 & 63;
      int jg = ((row>>5)<<9) + jt*32 + (row&31);
      int k = it*64 + kk;
      const float* src = (k < 512) ? (Whh + (long)jg*512 + k)
                                   : (Wih + (long)jg*1024 + (k - 512));
      *(s8x8*)(wcatp + s) = cast8(src);
    } else {
      long j = (c - CW)*8;
      *(s8x8*)(whp + j) = cast8(Wh + j);
    }
  }
}

// ---------------------------------------------------------------------------
// Late prepack (after t-loop; aliases dead wcatp/fvbf region): Wout -> bf16.
// ---------------------------------------------------------------------------
__global__ __launch_bounds__(256) void k_packout(const float* __restrict__ Wout,
                                                 short* __restrict__ woutbf)
{
  for (long c = blockIdx.x*256L + threadIdx.x; c < 640000; c += (long)gridDim.x*256L)
    *(s8x8*)(woutbf + c*8) = cast8(Wout + c*8);
}

// ---------------------------------------------------------------------------
// fvp = img @ Wv^T + att_b[r%49]  (bf16 out). Proven 128x128 template.
// grid (4, 49). K=512, fp32 sources inline-cast (runs once).
// ---------------------------------------------------------------------------
__global__ __launch_bounds__(256) void k_fv(const float* __restrict__ img,
    const float* __restrict__ Wv, const float* __restrict__ attb,
    short* __restrict__ fvbf)
{
  const int n0 = blockIdx.x*128, m0 = blockIdx.y*128;
  __shared__ short As[128*40];
  __shared__ short Bs[128*40];
  const int tid = threadIdx.x, w = tid>>6, lane = tid&63;
  f32x4 acc[8][2] = {};
  for (int k0 = 0; k0 < 512; k0 += 32){
    for (int c = tid; c < 512; c += 256){
      int row = c>>2, ko = (c&3)*8;
      *(s8x8*)(As + row*40 + ko) = cast8(img + (long)(m0+row)*512 + k0 + ko);
      *(s8x8*)(Bs + row*40 + ko) = cast8(Wv  + (long)(n0+row)*512 + k0 + ko);
    }
    __syncthreads();
    const int kb = (lane>>4)*8, l15 = lane&15;
    s8x8 b0f = *(const s8x8*)(Bs + (w*32 + l15)*40 + kb);
    s8x8 b1f = *(const s8x8*)(Bs + (w*32 + 16 + l15)*40 + kb);
    #pragma unroll
    for (int mt = 0; mt < 8; mt++){
      s8x8 a = *(const s8x8*)(As + (mt*16 + l15)*40 + kb);
      acc[mt][0] = mfma16(a, b0f, acc[mt][0]);
      acc[mt][1] = mfma16(a, b1f, acc[mt][1]);
    }
    __syncthreads();
  }
  const int l15 = lane&15;
  #pragma unroll
  for (int mt = 0; mt < 8; mt++){
    int rb = m0 + mt*16 + ((lane>>4)<<2);
    #pragma unroll
    for (int nt = 0; nt < 2; nt++){
      int cg = n0 + w*32 + nt*16 + l15;
      #pragma unroll
      for (int rr = 0; rr < 4; rr++){
        int r = rb + rr;
        fvbf[(long)r*512 + cg] = f2bf(acc[mt][nt][rr] + attb[r % NN]);
      }
    }
  }
}

// ---------------------------------------------------------------------------
// Attention step with fused oh (VALU). One block per b.
// t==0: ctx = mean_n img; alphas = 0.
// t>=1: oh = h@Wh^T (bf16 whp, LDS-broadcast h); e = sum relu(fv+oh)*Wa;
//       softmax; ctx = sum_n a*img (fp32) -> Cbuf bf16.
// ---------------------------------------------------------------------------
__global__ __launch_bounds__(256) void k_att(const short* __restrict__ Hcur,
    const short* __restrict__ whp, const short* __restrict__ fvbf,
    const float* __restrict__ Wa, const float* __restrict__ img,
    short* __restrict__ Cbuf, float* __restrict__ alph, int t)
{
  const int b = blockIdx.x, tid = threadIdx.x;
  if (t == 0){
    for (int d = tid; d < 512; d += 256){
      float s = 0.f;
      for (int n = 0; n < NN; n++) s += img[((long)b*NN + n)*512 + d];
      Cbuf[b*512 + d] = f2bf(s * (1.f/49.f));
    }
    if (tid < NN) alph[((long)b*NN + tid)*TT] = 0.f;
    return;
  }
  __shared__ float hs[512];
  __shared__ float ohs[512];
  __shared__ float ee[64];
  __shared__ float zp[4][512];
  for (int d = tid; d < 512; d += 256) hs[d] = bf2f(Hcur[b*512 + d]);
  __syncthreads();
  // oh[d] = sum_j h[j] * Wh[d][j]  (hs broadcast from LDS, bf16 weight rows)
  for (int d = tid; d < 512; d += 256){
    const short* wr = whp + (long)d*512;
    float s = 0.f;
    for (int j8 = 0; j8 < 512; j8 += 8){
      s8x8 v = *(const s8x8*)(wr + j8);
      #pragma unroll
      for (int q = 0; q < 8; q++) s = fmaf(hs[j8+q], bf2f(v[q]), s);
    }
    ohs[d] = s;
  }
  __syncthreads();
  const int w = tid>>6, lane = tid&63;
  float ohr[8], war[8];
  {
    const float* wp = Wa + lane*8;
    #pragma unroll
    for (int q = 0; q < 8; q++){ ohr[q] = ohs[lane*8 + q]; war[q] = wp[q]; }
  }
  for (int n = w; n < NN; n += 4){
    s8x8 v = *(const s8x8*)(fvbf + ((long)b*NN + n)*512 + lane*8);
    float s = 0.f;
    #pragma unroll
    for (int q = 0; q < 8; q++)
      s = fmaf(fmaxf(bf2f(v[q]) + ohr[q], 0.f), war[q], s);
    #pragma unroll
    for (int off = 32; off; off >>= 1) s += __shfl_xor(s, off);
    if (lane == 0) ee[n] = s;
  }
  __syncthreads();
  if (tid < 64){
    float e = (tid < NN) ? ee[tid] : -1e30f;
    float m = e;
    #pragma unroll
    for (int off = 32; off; off >>= 1) m = fmaxf(m, __shfl_xor(m, off));
    float ex = (tid < NN) ? __expf(e - m) : 0.f;
    float s = ex;
    #pragma unroll
    for (int off = 32; off; off >>= 1) s += __shfl_xor(s, off);
    float a = ex / s;
    if (tid < NN){ ee[tid] = a; alph[((long)b*NN + tid)*TT + t] = a; }
  }
  __syncthreads();
  const int cq = tid>>6, d0 = (tid&63)*8;
  float z[8] = {0,0,0,0,0,0,0,0};
  for (int n = cq; n < NN; n += 4){
    float an = ee[n];
    const float* ip = img + ((long)b*NN + n)*512 + d0;
    float4 u0 = *(const float4*)ip;
    float4 u1 = *(const float4*)(ip + 4);
    z[0] = fmaf(an, u0.x, z[0]); z[1] = fmaf(an, u0.y, z[1]);
    z[2] = fmaf(an, u0.z, z[2]); z[3] = fmaf(an, u0.w, z[3]);
    z[4] = fmaf(an, u1.x, z[4]); z[5] = fmaf(an, u1.y, z[5]);
    z[6] = fmaf(an, u1.z, z[6]); z[7] = fmaf(an, u1.w, z[7]);
  }
  #pragma unroll
  for (int q = 0; q < 8; q++) zp[cq][d0 + q] = z[q];
  __syncthreads();
  if (tid < 64){
    int dd = tid*8;
    s8x8 o;
    #pragma unroll
    for (int q = 0; q < 8; q++)
      o[q] = f2bf(zp[0][dd+q] + zp[1][dd+q] + zp[2][dd+q] + zp[3][dd+q]);
    *(s8x8*)(Cbuf + b*512 + dd) = o;
  }
}

// ---------------------------------------------------------------------------
// Gates + LSTM cell. grid (16 jt, 8 bt). M=16 batch rows, N=128 packed gate
// cols (q*32+jc), K=1536 = [h(Hcur) | ctx(Cbuf) | emb(inline-cast gather)].
// BK=64, register-prefetch pipeline, B-stream fully linear from wcatp.
// ---------------------------------------------------------------------------
__global__ __launch_bounds__(256) void k_gat(const short* __restrict__ Hcur,
    const short* __restrict__ Cbuf, const short* __restrict__ wcatp,
    const float* __restrict__ embed, const int* __restrict__ caps,
    const float* __restrict__ bih, const float* __restrict__ bhh,
    float* __restrict__ cst, short* __restrict__ Hnxt,
    short* __restrict__ Hall, int t)
{
  const int jt = blockIdx.x, b0 = blockIdx.y*16;
  const int J0 = jt*32;
  __shared__ short As[16*76];
  __shared__ short Bs[128*76];
  __shared__ float gs[16][132];
  const int tid = threadIdx.x, w = tid>>6, lane = tid&63;
  const long wbase = (long)jt*24*8192;

  s8x8 a_r, b_r[4];
  auto stage_load = [&](int it){
    if (tid < 128){
      int row = tid>>3, kkc = (tid&7)*8;
      int k = it*64 + kkc, gb = b0 + row;
      s8x8 av = {0,0,0,0,0,0,0,0};
      if (k < 512){
        if (t != 0) av = *(const s8x8*)(Hcur + (long)gb*512 + k);
      } else if (k < 1024){
        av = *(const s8x8*)(Cbuf + (long)gb*512 + (k - 512));
      } else {
        av = cast8(embed + (long)caps[gb*TT + t]*512 + (k - 1024));
      }
      a_r = av;
    }
    #pragma unroll
    for (int i = 0; i < 4; i++){
      long c = tid + i*256;
      b_r[i] = *(const s8x8*)(wcatp + wbase + (long)it*8192 + c*8);
    }
  };

  f32x4 acc[2] = {};
  stage_load(0);
  for (int it = 0; it < 24; ++it){
    if (tid < 128)
      *(s8x8*)(As + (tid>>3)*76 + (tid&7)*8) = a_r;
    #pragma unroll
    for (int i = 0; i < 4; i++){
      int c = tid + i*256;
      *(s8x8*)(Bs + (c>>3)*76 + (c&7)*8) = b_r[i];
    }
    __syncthreads();
    if (it < 23) stage_load(it + 1);
    const int kb = (lane>>4)*8, l15 = lane&15, cw = w*32;
    #pragma unroll
    for (int ks = 0; ks < 2; ks++){
      s8x8 b0f = *(const s8x8*)(Bs + (cw + l15)*76 + kb + ks*32);
      s8x8 b1f = *(const s8x8*)(Bs + (cw + 16 + l15)*76 + kb + ks*32);
      s8x8 a = *(const s8x8*)(As + l15*76 + kb + ks*32);
      acc[0] = mfma16(a, b0f, acc[0]);
      acc[1] = mfma16(a, b1f, acc[1]);
    }
    __syncthreads();
  }
  {
    const int l15 = lane&15;
    int rl = (lane>>4)<<2;
    #pragma unroll
    for (int nt = 0; nt < 2; nt++){
      int ct = w*32 + nt*16 + l15;
      #pragma unroll
      for (int rr = 0; rr < 4; rr++)
        gs[rl+rr][ct] = acc[nt][rr];
    }
  }
  __syncthreads();
  for (int task = tid; task < 512; task += 256){
    int bl = task>>5, jc = task&31;
    int gb = b0 + bl, j = J0 + jc;
    float gi = gs[bl][jc]      + bih[j]        + bhh[j];
    float gf = gs[bl][32+jc]   + bih[512+j]    + bhh[512+j];
    float gg = gs[bl][64+jc]   + bih[1024+j]   + bhh[1024+j];
    float go = gs[bl][96+jc]   + bih[1536+j]   + bhh[1536+j];
    float ii = 1.f/(1.f+__expf(-gi));
    float ff = 1.f/(1.f+__expf(-gf));
    float e2 = __expf(2.f*gg); float g2 = (e2-1.f)/(e2+1.f);
    float oo = 1.f/(1.f+__expf(-go));
    float cp = (t == 0) ? 0.f : cst[gb*512 + j];
    float cN = ff*cp + ii*g2;
    float e3 = __expf(2.f*cN); float th = (e3-1.f)/(e3+1.f);
    float hN = oo*th;
    cst[gb*512 + j] = cN;
    short hb = f2bf(hN);
    Hnxt[gb*512 + j] = hb;
    Hall[((long)gb*TT + t)*512 + j] = hb;
  }
}

// ---------------------------------------------------------------------------
// Final GEMM: preds = Hall(bf16) @ woutbf(bf16)^T + bout.
// Proven template + bijective XCD-chunked swizzle (n-major: 20 consecutive
// wg share one B panel) + XOR-chunk LDS swizzle (kills 8-way conflicts).
// ---------------------------------------------------------------------------
__global__ __launch_bounds__(256) void k_out(const short* __restrict__ Abf,
    const short* __restrict__ Bbf, float* __restrict__ outf,
    const float* __restrict__ bias)
{
  // XCD-bijective remap of 1580 blocks (q=197, r=4)
  int flat = blockIdx.y*79 + blockIdx.x;
  int xcd = flat & 7, idx = flat >> 3;
  int wg = (xcd < 4) ? xcd*198 + idx : 792 + (xcd-4)*197 + idx;
  const int n0 = (wg/20)*128, m0 = (wg%20)*128;
  __shared__ short As[128*40];
  __shared__ short Bs[128*40];
  const int tid = threadIdx.x, w = tid>>6, lane = tid&63;
  f32x4 acc[8][2] = {};
  for (int k0 = 0; k0 < 512; k0 += 32){
    for (int c = tid; c < 512; c += 256){
      int row = c>>2, ko = (c&3)*8;
      int kos = ((c&3) ^ (row&3))*8;     // XOR-chunk swizzled position
      *(s8x8*)(As + row*40 + kos) = *(const s8x8*)(Abf + (long)(m0+row)*512 + k0 + ko);
      int brow = n0 + row;
      s8x8 bv = {0,0,0,0,0,0,0,0};
      if (brow < VV) bv = *(const s8x8*)(Bbf + (long)brow*512 + k0 + ko);
      *(s8x8*)(Bs + row*40 + kos) = bv;
    }
    __syncthreads();
    const int l15 = lane&15;
    const int kb = (((lane>>4) ^ (l15&3)))*8;  // reads back chunk lane>>4
    s8x8 b0f = *(const s8x8*)(Bs + (w*32 + l15)*40 + kb);
    s8x8 b1f = *(const s8x8*)(Bs + (w*32 + 16 + l15)*40 + kb);
    #pragma unroll
    for (int mt = 0; mt < 8; mt++){
      s8x8 a = *(const s8x8*)(As + (mt*16 + l15)*40 + kb);
      acc[mt][0] = mfma16(a, b0f, acc[mt][0]);
      acc[mt][1] = mfma16(a, b1f, acc[mt][1]);
    }
    __syncthreads();
  }
  const int l15 = lane&15;
  #pragma unroll
  for (int mt = 0; mt < 8; mt++){
    int rb = m0 + mt*16 + ((lane>>4)<<2);
    #pragma unroll
    for (int nt = 0; nt < 2; nt++){
      int cg = n0 + w*32 + nt*16 + l15;
      if (cg >= VV) continue;
      #pragma unroll
      for (int rr = 0; rr < 4; rr++){
        int r = rb + rr;
        outf[(long)r*VV + cg] = acc[mt][nt][rr] + bias[cg];
      }
    }
  }
}

// ---------------------------------------------------------------------------
extern "C" void kernel_launch(void* const* d_in, const int* in_sizes, int n_in,
                              void* d_out, int out_size, void* d_ws, size_t ws_size,
                              hipStream_t stream)
{
  const float* img  = (const float*)d_in[0];
  const int*   caps = (const int*)d_in[1];
  const float* emb  = (const float*)d_in[2];
  const float* Wv   = (const float*)d_in[3];
  const float* Wh   = (const float*)d_in[4];
  const float* attb = (const float*)d_in[5];
  const float* Wa   = (const float*)d_in[6];
  const float* Wih  = (const float*)d_in[7];
  const float* bih  = (const float*)d_in[8];
  const float* Whh  = (const float*)d_in[9];
  const float* bhh  = (const float*)d_in[10];
  const float* Wout = (const float*)d_in[11];
  const float* bout = (const float*)d_in[12];
  float* preds = (float*)d_out;
  float* alph  = preds + (long)BB*TT*VV;

  // Workspace layout: exactly 16,777,216 B (proven available).
  char* ws = (char*)d_ws;
  short* wcatp  = (short*)(ws);              // 6,291,456 B
  short* whp    = (short*)(ws + 6291456);    //   524,288 B
  short* fvbf   = (short*)(ws + 6815744);    // 6,422,528 B
  short* Hbuf   = (short*)(ws + 13238272);   //   262,144 B (2 x [128][512] bf16)
  short* Cbuf   = (short*)(ws + 13500416);   //   131,072 B
  float* cst    = (float*)(ws + 13631488);   //   262,144 B
  short* Hall   = (short*)(ws + 13893632);   // 2,621,440 B -> 16,515,072
  short* woutbf = (short*)(ws);              // alias over wcatp/whp/fvbf (dead
                                             // after t-loop); 10,240,000 B

  k_prep2<<<1024, 256, 0, stream>>>(Whh, Wih, Wh, wcatp, whp);
  k_fv<<<dim3(4,49), 256, 0, stream>>>(img, Wv, attb, fvbf);

  for (int t = 0; t < TT; t++){
    short* Hc = Hbuf + (t&1)*65536;
    short* Hn = Hbuf + ((t+1)&1)*65536;
    k_att<<<128, 256, 0, stream>>>(Hc, whp, fvbf, Wa, img, Cbuf, alph, t);
    k_gat<<<dim3(16,8), 256, 0, stream>>>(Hc, Cbuf, wcatp, emb, caps, bih, bhh,
                                          cst, Hn, Hall, t);
  }

  k_packout<<<1024, 256, 0, stream>>>(Wout, woutbf);
  k_out<<<dim3(79,20), 256, 0, stream>>>(Hall, woutbf, preds, bout);
}